// Round 8
// baseline (604.187 us; speedup 1.0000x reference)
//
#include <hip/hip_runtime.h>

// ---------------- problem constants ----------------
#define Kc 8
#define Bc 64
#define Tc 128
#define Yc 128
#define Xc 64
#define Hc 256
#define Rc 8192   // B*T

typedef unsigned short u16;
typedef unsigned int u32;
typedef __attribute__((ext_vector_type(8))) short short8;  // 8 bf16 (4 VGPR)
typedef __attribute__((ext_vector_type(4))) float f32x4;   // MFMA C/D
typedef __attribute__((ext_vector_type(2))) unsigned int u32x2;

// ---------------- ws layout (u16 element offsets) ----------------
#define OFF_DATA 0L         // data bf16        [8192][128] row-major
#define OFF_YWIH 1048576L   // y_Wih bf16       [8][256][128] row-major
#define OFF_YWHH 1310720L   // y_Whh bf16       [8][256][256] row-major
#define OFF_YWMU 1835008L   // y_Wmu bf16       [8][64][256] row-major
#define OFF_XWIH 1966080L   // x_Wih bf16       [8][256][64] row-major
#define OFF_XWHH 2097152L   // x_Whh bf16       [8][256][256] row-major
#define OFF_M2   2621440L   // M2 = W2@dsW bf16 [16(pad)][2048] row-major
#define OFF_XWT  6848512L   // xW_y frag tiles  [8][4 bs][128 t][4096]
#define U16_BYTES 80805888L
// f32 region (after u16 region)
#define FO_YB 0L       // y bias (bih+bhh) [8][256]
#define FO_XB 2048L    // x bias           [8][256]
#define FO_CB 4096L    // combiner const   [16]
#define FO_A2 4112L    // A2 = W2@W1       [8][8]
#define FO_CP 8192L    // c partials       [8][8192][8]
#define FO_C  532480L  // c summed         [8192][8]
#define FO_W  598016L  // sparsemax w      [8192][8]

// frag-major tile (16 batch m x N hidden n):
//   u16 idx(m,n) = (n>>5)*512 + ((n>>3)&3)*128 + m*8 + (n&7)
// B-frag read (lane l, kk): idx = kk*512 + (l>>4)*128 + (l&15)*8  (16B contiguous)
// D write (lane l, nt): n = wv*64+nt*16+lk*4+r ->
//   roff = (wv*2+(nt>>1))*512 + ((nt&1)*2+(lk>>1))*128 + lr*8 + (lk&1)*4

// ---------------- output layout (f32 elements) ----------------
#define O_XS  0L        // x_sample   [64][128][64]
#define O_QMU 524288L   // q_x_mu     [8][64][128][64]
#define O_QLV 4718592L  // q_x_logvar [8][64][128][64] (zeros)
#define O_ZS  8912896L  // z_sample   [64][128][8]
#define O_ZL  8978432L  // z_logits   [64][128][8]

// ---------------- helpers ----------------
__device__ __forceinline__ u16 f2bf(float f) {
  union { float f; u32 u; } v; v.f = f;
  u32 u = v.u;
  return (u16)((u + 0x7FFFu + ((u >> 16) & 1u)) >> 16);  // RNE
}
__device__ __forceinline__ float bitsf(u32 u) {
  union { u32 u; float f; } v; v.u = u; return v.f;
}
__device__ __forceinline__ u32 cvt_pk(float lo, float hi) {
  u32 r;
  asm("v_cvt_pk_bf16_f32 %0, %1, %2" : "=v"(r) : "v"(lo), "v"(hi));
  return r;
}
__device__ __forceinline__ f32x4 mfma16(short8 a, short8 b, f32x4 c) {
  return __builtin_amdgcn_mfma_f32_16x16x32_bf16(a, b, c, 0, 0, 0);
}

// ---------------- P1: dtype conversions, biases, zero logvar ----------------
__global__ void k_prep(const float* __restrict__ data, const float* __restrict__ yWih,
                       const float* __restrict__ yWhh, const float* __restrict__ yWmu,
                       const float* __restrict__ xWih, const float* __restrict__ xWhh,
                       const float* __restrict__ ybih, const float* __restrict__ ybhh,
                       const float* __restrict__ xbih, const float* __restrict__ xbhh,
                       u16* __restrict__ W, float* __restrict__ F, float* __restrict__ out)
{
  long tid = (long)blockIdx.x * blockDim.x + threadIdx.x;
  long stride = (long)gridDim.x * blockDim.x;
  for (long i = tid; i < 1048576L; i += stride) W[OFF_DATA + i] = f2bf(data[i]);
  for (long i = tid; i < 262144L;  i += stride) W[OFF_YWIH + i] = f2bf(yWih[i]);
  for (long i = tid; i < 524288L;  i += stride) W[OFF_YWHH + i] = f2bf(yWhh[i]);
  for (long i = tid; i < 131072L;  i += stride) W[OFF_YWMU + i] = f2bf(yWmu[i]);
  for (long i = tid; i < 131072L;  i += stride) W[OFF_XWIH + i] = f2bf(xWih[i]);
  for (long i = tid; i < 524288L;  i += stride) W[OFF_XWHH + i] = f2bf(xWhh[i]);
  for (long i = tid; i < 2048L;    i += stride) F[FO_YB + i] = ybih[i] + ybhh[i];
  for (long i = tid; i < 2048L;    i += stride) F[FO_XB + i] = xbih[i] + xbhh[i];
  for (long i = tid; i < 4194304L; i += stride) out[O_QLV + i] = 0.0f;
}

// ---------------- P2: combiner collapse  M2 = W2@dsW,  A2 = W2@W1,  cbias ----------------
__global__ void k_prep2(const float* __restrict__ dsW, const float* __restrict__ dsb,
                        const float* __restrict__ W1, const float* __restrict__ b1,
                        const float* __restrict__ W2, const float* __restrict__ b2,
                        u16* __restrict__ W, float* __restrict__ F)
{
  if (blockIdx.x < 128) {  // M2 [16][2048] (rows >=8 zero-padded)
    long i = (long)blockIdx.x * 256 + threadIdx.x;   // 0..32767
    int k2 = (int)(i >> 11), ki = (int)(i & 2047);
    float s = 0.0f;
    if (k2 < 8) {
      for (int j = 0; j < 256; ++j) s += W2[k2 * 256 + j] * dsW[(long)j * 2048 + ki];
    }
    W[OFF_M2 + i] = f2bf(s);
  } else {  // blockIdx.x == 128
    int t = threadIdx.x;
    if (t < 64) {            // A2[k2][k1] = sum_j W2[k2,j] W1[j,k1]
      int k2 = t >> 3, k1 = t & 7;
      float s = 0.0f;
      for (int j = 0; j < 256; ++j) s += W2[k2 * 256 + j] * W1[j * 8 + k1];
      F[FO_A2 + t] = s;
    } else if (t < 80) {     // cbias[k2] = W2@(dsb+b1) + b2   (pad to 16)
      int k2 = t - 64;
      float s = 0.0f;
      if (k2 < 8) {
        for (int j = 0; j < 256; ++j) s += W2[k2 * 256 + j] * (dsb[j] + b1[j]);
        s += b2[k2];
      }
      F[FO_CB + k2] = s;
    }
  }
}

// ---------------- G1: xW_y = y_Wih(A) x data(B) + ybias -> frag tiles ----------------
// grid (4 bsplit * 32 tchunk, 8 k), 256 thr (4 waves = 4 n-stripes of 64), 4 t per block
__global__ __launch_bounds__(256) void k_g1(const u16* __restrict__ W, const float* __restrict__ F,
                                            u16* __restrict__ buf)
{
  const int k = blockIdx.y, bs = blockIdx.x >> 5, t0 = (blockIdx.x & 31) * 4;
  const int tid = threadIdx.x, wv = tid >> 6, l = tid & 63, lr = l & 15, lk = l >> 4;
  const int b0 = bs * 16;
  short8 Af[4][4];
  const u16* Ak = W + OFF_YWIH + (long)k * 32768;
#pragma unroll
  for (int nt = 0; nt < 4; ++nt)
#pragma unroll
    for (int kk = 0; kk < 4; ++kk)
      Af[nt][kk] = *(const short8*)(Ak + (long)(wv * 64 + nt * 16 + lr) * 128 + kk * 32 + lk * 8);
  f32x4 bias[4];
#pragma unroll
  for (int nt = 0; nt < 4; ++nt)
    bias[nt] = *(const f32x4*)&F[FO_YB + k * 256 + wv * 64 + nt * 16 + lk * 4];
  int roff[4];
#pragma unroll
  for (int nt = 0; nt < 4; ++nt)
    roff[nt] = (wv * 2 + (nt >> 1)) * 512 + ((nt & 1) * 2 + (lk >> 1)) * 128 + lr * 8 + (lk & 1) * 4;

  for (int ti = 0; ti < 4; ++ti) {
    int t = t0 + ti;
    f32x4 acc[4] = {bias[0], bias[1], bias[2], bias[3]};
    const u16* Brow = W + OFF_DATA + ((long)(b0 + lr) * 128 + t) * 128 + lk * 8;
#pragma unroll
    for (int kk = 0; kk < 4; ++kk) {
      short8 b = *(const short8*)(Brow + kk * 32);
      acc[0] = mfma16(Af[0][kk], b, acc[0]);
      acc[1] = mfma16(Af[1][kk], b, acc[1]);
      acc[2] = mfma16(Af[2][kk], b, acc[2]);
      acc[3] = mfma16(Af[3][kk], b, acc[3]);
    }
    u16* tb = buf + ((long)(k * 4 + bs) * 128 + t) * 4096;
#pragma unroll
    for (int nt = 0; nt < 4; ++nt) {
      u32 d0 = cvt_pk(acc[nt][0], acc[nt][1]);
      u32 d1 = cvt_pk(acc[nt][2], acc[nt][3]);
      *(u32x2*)(tb + roff[nt]) = (u32x2){d0, d1};
    }
  }
}

// ---------------- R2: fused y-RNN || x-RNN mega-kernel ----------------
// grid (4 bs, 8 k), 512 thr. waves 0-3: y-chain; waves 4-7: x-chain (2-step lag).
// y: h_y(t) = relu(xw(t) + Whh_y@h_y(t+1));  mu(tau) = Wmu@h_y(tau) (reuses b-frags);
//    q_x(tau) = mu + eps -> LDS ring -> x-chain.  mu -> out (q_x_mu).
// x: h_x(t) = relu(Wih_x@q_x(t) + Whh_x@h_x(t+1) + bx);  cp(t+1) = M2_k@h_x(t+1).
__global__ __launch_bounds__(512, 1) void k_rnn2(const u16* __restrict__ W,
                                                 const float* __restrict__ F,
                                                 const float* __restrict__ eps_qx,
                                                 const float* __restrict__ bmu,
                                                 const float* __restrict__ yh0,
                                                 const float* __restrict__ xh0,
                                                 float* __restrict__ out,
                                                 float* __restrict__ cpart)
{
  const int k = blockIdx.y, bs = blockIdx.x, b0 = bs * 16;
  const int tid = threadIdx.x;
  const int ch = tid >> 8;              // 0 = y-chain, 1 = x-chain
  const int wv = (tid >> 6) & 3;
  const int l = tid & 63, lr = l & 15, lk = l >> 4;
  const int fro = lk * 128 + lr * 8;
  __shared__ __align__(16) u16 hyL[2][4096];
  __shared__ __align__(16) u16 hxL[2][4096];
  __shared__ __align__(16) u16 qrL[2][1024];

  int roff[4];
#pragma unroll
  for (int nt = 0; nt < 4; ++nt)
    roff[nt] = (wv * 2 + (nt >> 1)) * 512 + ((nt & 1) * 2 + (lk >> 1)) * 128 + lr * 8 + (lk & 1) * 4;

  // ---- resident weights (per chain role) ----
  short8 Bf[4][8];   // Whh (y or x)
  short8 Af[8];      // y: Wmu rows x0..x0+16
  short8 IhX[4][2];  // x: Wih_x
  short8 Mf[8];      // x wave0: M2 slice
  f32x4 mbias;       // y: bmu
  f32x4 xbias[4];    // x: xb
  const int x0 = wv * 16;
  if (ch == 0) {
    const u16* Wk = W + OFF_YWHH + (long)k * 65536;
#pragma unroll
    for (int nt = 0; nt < 4; ++nt)
#pragma unroll
      for (int kk = 0; kk < 8; ++kk)
        Bf[nt][kk] = *(const short8*)(Wk + (long)(wv * 64 + nt * 16 + lr) * 256 + kk * 32 + lk * 8);
    const u16* Ak = W + OFF_YWMU + (long)k * 16384;
#pragma unroll
    for (int kk = 0; kk < 8; ++kk)
      Af[kk] = *(const short8*)(Ak + (long)(x0 + lr) * 256 + kk * 32 + lk * 8);
    mbias = *(const f32x4*)&bmu[k * 64 + x0 + lk * 4];
  } else {
    const u16* Wk = W + OFF_XWHH + (long)k * 65536;
    const u16* Ik = W + OFF_XWIH + (long)k * 16384;
#pragma unroll
    for (int nt = 0; nt < 4; ++nt) {
#pragma unroll
      for (int kk = 0; kk < 8; ++kk)
        Bf[nt][kk] = *(const short8*)(Wk + (long)(wv * 64 + nt * 16 + lr) * 256 + kk * 32 + lk * 8);
#pragma unroll
      for (int kk = 0; kk < 2; ++kk)
        IhX[nt][kk] = *(const short8*)(Ik + (long)(wv * 64 + nt * 16 + lr) * 64 + kk * 32 + lk * 8);
      xbias[nt] = *(const f32x4*)&F[FO_XB + k * 256 + wv * 64 + nt * 16 + lk * 4];
    }
    if (wv == 0) {
      const u16* Mk = W + OFF_M2 + (long)k * 256;
#pragma unroll
      for (int kk = 0; kk < 8; ++kk)
        Mf[kk] = *(const short8*)(Mk + (long)lr * 2048 + kk * 32 + lk * 8);
    }
  }

  // ---- h0 init ----
  for (int i = tid; i < 4096; i += 512) {
    int n = (i >> 9) * 32 + ((i >> 7) & 3) * 8 + (i & 7);
    hyL[0][i] = f2bf(yh0[k * 256 + n]);
    hxL[0][i] = f2bf(xh0[k * 256 + n]);
  }

  const u16* xwb = W + OFF_XWT + (long)(k * 4 + bs) * 128 * 4096;
  const int qoff = (wv >> 1) * 512 + ((wv & 1) * 2 + (lk >> 1)) * 128 + lr * 8 + (lk & 1) * 4;
  float* cp = cpart + (long)k * Rc * 8;

  // y preload xw(Tc-1)
  u32 xwc[8];
  if (ch == 0) {
#pragma unroll
    for (int nt = 0; nt < 4; ++nt) {
      u32x2 v = *(const u32x2*)(xwb + (long)(Tc - 1) * 4096 + roff[nt]);
      xwc[nt * 2] = v.x; xwc[nt * 2 + 1] = v.y;
    }
  }
  __syncthreads();

  int p = 0, px = 0;
  for (int s = 0; s <= Tc + 1; ++s) {
    if (ch == 0) {
      const int t_y = Tc - 1 - s;          // recurrence target (valid s<Tc)
      const int tau = Tc - s;              // mu/qx target (valid 1<=s<=Tc)
      u32 xwn[8];
      if (t_y > 0) {
#pragma unroll
        for (int nt = 0; nt < 4; ++nt) {
          u32x2 v = *(const u32x2*)(xwb + (long)(t_y - 1) * 4096 + roff[nt]);
          xwn[nt * 2] = v.x; xwn[nt * 2 + 1] = v.y;
        }
      }
      f32x4 e;
      if (s >= 1 && s <= Tc)
        e = *(const f32x4*)&eps_qx[(((long)k * 64 + b0 + lr) * 128 + tau) * 64 + x0 + lk * 4];
      f32x4 acc[4];
      if (s < Tc) {
#pragma unroll
        for (int nt = 0; nt < 4; ++nt) {
          u32 w0 = xwc[nt * 2], w1 = xwc[nt * 2 + 1];
          acc[nt][0] = bitsf(w0 << 16);
          acc[nt][1] = bitsf(w0 & 0xffff0000u);
          acc[nt][2] = bitsf(w1 << 16);
          acc[nt][3] = bitsf(w1 & 0xffff0000u);
        }
      }
      f32x4 macc = mbias;
      if (s <= Tc) {
#pragma unroll
        for (int kk = 0; kk < 8; ++kk) {
          short8 b = *(const short8*)&hyL[p][kk * 512 + fro];
          if (s < Tc) {
            acc[0] = mfma16(Bf[0][kk], b, acc[0]);
            acc[1] = mfma16(Bf[1][kk], b, acc[1]);
            acc[2] = mfma16(Bf[2][kk], b, acc[2]);
            acc[3] = mfma16(Bf[3][kk], b, acc[3]);
          }
          macc = mfma16(Af[kk], b, macc);
        }
      }
      if (s >= 1 && s <= Tc) {
        // q_x_mu(tau) -> out;  q_x(tau) = mu + eps -> ring
        long idx = (((long)k * 64 + b0 + lr) * 128 + tau) * 64 + x0 + lk * 4;
        *(f32x4*)&out[O_QMU + idx] = macc;
        f32x4 q = macc + e;
        *(u32x2*)&qrL[tau & 1][qoff] = (u32x2){cvt_pk(q[0], q[1]), cvt_pk(q[2], q[3])};
      }
      if (s < Tc) {
#pragma unroll
        for (int nt = 0; nt < 4; ++nt) {
          float f0 = fmaxf(acc[nt][0], 0.0f), f1 = fmaxf(acc[nt][1], 0.0f);
          float f2 = fmaxf(acc[nt][2], 0.0f), f3 = fmaxf(acc[nt][3], 0.0f);
          *(u32x2*)&hyL[p ^ 1][roff[nt]] = (u32x2){cvt_pk(f0, f1), cvt_pk(f2, f3)};
        }
      }
#pragma unroll
      for (int i = 0; i < 8; ++i) xwc[i] = xwn[i];
    } else {
      const int t_x = Tc + 1 - s;          // valid 2<=s<=Tc+1
      if (s >= 2) {
        short8 qc[2];
#pragma unroll
        for (int kk = 0; kk < 2; ++kk)
          qc[kk] = *(const short8*)&qrL[t_x & 1][kk * 512 + fro];
        f32x4 acc[4] = {xbias[0], xbias[1], xbias[2], xbias[3]};
        f32x4 cacc = (f32x4){0.f, 0.f, 0.f, 0.f};
#pragma unroll
        for (int kk = 0; kk < 8; ++kk) {
          short8 b = *(const short8*)&hxL[px][kk * 512 + fro];
          acc[0] = mfma16(Bf[0][kk], b, acc[0]);
          acc[1] = mfma16(Bf[1][kk], b, acc[1]);
          acc[2] = mfma16(Bf[2][kk], b, acc[2]);
          acc[3] = mfma16(Bf[3][kk], b, acc[3]);
          if (wv == 0) cacc = mfma16(Mf[kk], b, cacc);
        }
#pragma unroll
        for (int kk = 0; kk < 2; ++kk) {
          acc[0] = mfma16(IhX[0][kk], qc[kk], acc[0]);
          acc[1] = mfma16(IhX[1][kk], qc[kk], acc[1]);
          acc[2] = mfma16(IhX[2][kk], qc[kk], acc[2]);
          acc[3] = mfma16(IhX[3][kk], qc[kk], acc[3]);
        }
        if (wv == 0 && s >= 3 && lk < 2)
          *(f32x4*)&cp[((long)(b0 + lr) * Tc + (t_x + 1)) * 8 + lk * 4] = cacc;
#pragma unroll
        for (int nt = 0; nt < 4; ++nt) {
          float f0 = fmaxf(acc[nt][0], 0.0f), f1 = fmaxf(acc[nt][1], 0.0f);
          float f2 = fmaxf(acc[nt][2], 0.0f), f3 = fmaxf(acc[nt][3], 0.0f);
          *(u32x2*)&hxL[px ^ 1][roff[nt]] = (u32x2){cvt_pk(f0, f1), cvt_pk(f2, f3)};
        }
      }
    }
    asm volatile("s_waitcnt lgkmcnt(0)" ::: "memory");
    __builtin_amdgcn_s_barrier();
    __builtin_amdgcn_sched_barrier(0);
    if (ch == 0) { if (s < Tc) p ^= 1; }
    else         { if (s >= 2) px ^= 1; }
  }
  // epilogue: c(0) from h_x(0) (now in hxL[px])
  if (ch == 1 && wv == 0) {
    f32x4 cacc = (f32x4){0.f, 0.f, 0.f, 0.f};
#pragma unroll
    for (int kk = 0; kk < 8; ++kk) {
      short8 b = *(const short8*)&hxL[px][kk * 512 + fro];
      cacc = mfma16(Mf[kk], b, cacc);
    }
    if (lk < 2)
      *(f32x4*)&cp[((long)(b0 + lr) * Tc) * 8 + lk * 4] = cacc;
  }
}

// ---------------- CS: c = cbias + sum_k cpart_k ----------------
__global__ void k_csum(const float* __restrict__ cpart, const float* __restrict__ F,
                       float* __restrict__ cbuf)
{
  int i = blockIdx.x * 256 + threadIdx.x;  // < 65536
  float s = F[FO_CB + (i & 7)];
#pragma unroll
  for (int k = 0; k < 8; ++k) s += cpart[(long)k * 65536 + i];
  cbuf[i] = s;
}

// ---------------- S5a: z chain (one wave per batch element) ----------------
#define CASD(a, b) { float _hi = fmaxf(a, b), _lo = fminf(a, b); a = _hi; b = _lo; }
__global__ __launch_bounds__(256) void k_zchain(const float* __restrict__ F, const float* __restrict__ cbuf,
                                                const float* __restrict__ eps_z, const float* __restrict__ zq0,
                                                float* __restrict__ out, float* __restrict__ wbuf)
{
  const int wv = threadIdx.x >> 6, l = threadIdx.x & 63;
  const int b = blockIdx.x * 4 + wv;
  __shared__ float cl[4][1024];
  __shared__ float el[4][1024];
  for (int i = l; i < 1024; i += 64) cl[wv][i] = cbuf[(long)b * 1024 + i];
  for (int i = l; i < 1024; i += 64) {
    int t = i >> 3, kk = i & 7;
    el[wv][i] = eps_z[(long)t * (Bc * Kc) + b * 8 + kk];
  }
  float a2 = F[FO_A2 + l];   // A2[l>>3][l&7]
  __syncthreads();

  float z = zq0[l & 7];      // every lane holds z_prev[l&7]
  for (int t = 0; t < Tc; ++t) {
    float p = a2 * z;
    p += __shfl_xor(p, 1, 64);
    p += __shfl_xor(p, 2, 64);
    p += __shfl_xor(p, 4, 64);                  // group g=l>>3 holds sum_k1 A2[g][k1] z[k1]
    float zmu_l = __shfl(p, (l & 7) * 8, 64);   // lane l gets zmu_lin[l&7]
    float zl = zmu_l + cl[wv][t * 8 + (l & 7)]; // z_logits
    float zt = zl + el[wv][t * 8 + (l & 7)];    // z_sample

    // sparsemax over 8 values (all lanes redundantly)
    float v0 = __shfl(zt, 0, 64), v1 = __shfl(zt, 1, 64), v2 = __shfl(zt, 2, 64), v3 = __shfl(zt, 3, 64);
    float v4 = __shfl(zt, 4, 64), v5 = __shfl(zt, 5, 64), v6 = __shfl(zt, 6, 64), v7 = __shfl(zt, 7, 64);
    CASD(v0, v1); CASD(v2, v3); CASD(v4, v5); CASD(v6, v7);
    CASD(v0, v2); CASD(v1, v3); CASD(v4, v6); CASD(v5, v7);
    CASD(v1, v2); CASD(v5, v6);
    CASD(v0, v4); CASD(v1, v5); CASD(v2, v6); CASD(v3, v7);
    CASD(v2, v4); CASD(v3, v5);
    CASD(v1, v2); CASD(v3, v4); CASD(v5, v6);   // v0 >= v1 >= ... >= v7
    float s0 = v0, s1 = s0 + v1, s2 = s1 + v2, s3 = s2 + v3;
    float s4 = s3 + v4, s5 = s4 + v5, s6 = s5 + v6, s7 = s6 + v7;
    int kz = 1;
    kz += (2.0f * v1 > s1 - 1.0f) ? 1 : 0;
    kz += (3.0f * v2 > s2 - 1.0f) ? 1 : 0;
    kz += (4.0f * v3 > s3 - 1.0f) ? 1 : 0;
    kz += (5.0f * v4 > s4 - 1.0f) ? 1 : 0;
    kz += (6.0f * v5 > s5 - 1.0f) ? 1 : 0;
    kz += (7.0f * v6 > s6 - 1.0f) ? 1 : 0;
    kz += (8.0f * v7 > s7 - 1.0f) ? 1 : 0;
    float csel = s0 - 1.0f;
    csel = (kz > 1) ? s1 - 1.0f : csel;
    csel = (kz > 2) ? s2 - 1.0f : csel;
    csel = (kz > 3) ? s3 - 1.0f : csel;
    csel = (kz > 4) ? s4 - 1.0f : csel;
    csel = (kz > 5) ? s5 - 1.0f : csel;
    csel = (kz > 6) ? s6 - 1.0f : csel;
    csel = (kz > 7) ? s7 - 1.0f : csel;
    float tau = csel / (float)kz;
    float wk = fmaxf(zt - tau, 0.0f);

    if (l < 8) {
      long r = (long)b * Tc + t;
      out[O_ZL + r * 8 + l] = zl;
      out[O_ZS + r * 8 + l] = zt;
      wbuf[r * 8 + l] = wk;
    }
    z = zt;
  }
}

// ---------------- S5b: x_sample = sum_k w * mu + eps_x ----------------
__global__ void k_xsample(const float* __restrict__ wbuf, const float* __restrict__ eps_x,
                          float* __restrict__ out)
{
  long idx = (long)blockIdx.x * 256 + threadIdx.x;
  if (idx >= (long)Rc * Xc) return;
  long r = idx >> 6;          // b*T + t
  int x = (int)(idx & 63);
  long b = r >> 7;
  long t = r & 127;
  float s = eps_x[(t * Bc + b) * 64 + x];
#pragma unroll
  for (int k = 0; k < 8; ++k)
    s += wbuf[r * 8 + k] * out[O_QMU + ((long)k * Rc + r) * 64 + x];
  out[O_XS + idx] = s;
}

// ---------------- launch ----------------
extern "C" void kernel_launch(void* const* d_in, const int* in_sizes, int n_in,
                              void* d_out, int out_size, void* d_ws, size_t ws_size,
                              hipStream_t stream) {
  (void)in_sizes; (void)n_in; (void)out_size; (void)ws_size;
  const float* data   = (const float*)d_in[0];
  const float* eps_qx = (const float*)d_in[1];
  const float* eps_z  = (const float*)d_in[2];
  const float* eps_x  = (const float*)d_in[3];
  const float* yWih   = (const float*)d_in[4];
  const float* yWhh   = (const float*)d_in[5];
  const float* ybih   = (const float*)d_in[6];
  const float* ybhh   = (const float*)d_in[7];
  const float* yh0    = (const float*)d_in[8];
  const float* yWmu   = (const float*)d_in[9];
  const float* ybmu   = (const float*)d_in[10];
  const float* xWih   = (const float*)d_in[11];
  const float* xWhh   = (const float*)d_in[12];
  const float* xbih   = (const float*)d_in[13];
  const float* xbhh   = (const float*)d_in[14];
  const float* xh0    = (const float*)d_in[15];
  const float* dsW    = (const float*)d_in[16];
  const float* dsb    = (const float*)d_in[17];
  const float* cbW1   = (const float*)d_in[18];
  const float* cbb1   = (const float*)d_in[19];
  const float* cbW2   = (const float*)d_in[20];
  const float* cbb2   = (const float*)d_in[21];
  const float* zq0    = (const float*)d_in[22];

  u16*   W = (u16*)d_ws;
  float* F = (float*)((char*)d_ws + U16_BYTES);
  float* out = (float*)d_out;

  hipLaunchKernelGGL(k_prep, dim3(1024), dim3(256), 0, stream,
                     data, yWih, yWhh, yWmu, xWih, xWhh, ybih, ybhh, xbih, xbhh, W, F, out);
  hipLaunchKernelGGL(k_prep2, dim3(129), dim3(256), 0, stream,
                     dsW, dsb, cbW1, cbb1, cbW2, cbb2, W, F);
  hipLaunchKernelGGL(k_g1, dim3(128, 8), dim3(256), 0, stream, W, F, W + OFF_XWT);
  hipLaunchKernelGGL(k_rnn2, dim3(4, 8), dim3(512), 0, stream,
                     W, F, eps_qx, ybmu, yh0, xh0, out, F + FO_CP);
  hipLaunchKernelGGL(k_csum, dim3(256), dim3(256), 0, stream, F + FO_CP, F, F + FO_C);
  hipLaunchKernelGGL(k_zchain, dim3(16), dim3(256), 0, stream, F, F + FO_C, eps_z, zq0, out, F + FO_W);
  hipLaunchKernelGGL(k_xsample, dim3(2048), dim3(256), 0, stream, F + FO_W, eps_x, out);
}

// Round 9
// 328.628 us; speedup vs baseline: 1.8385x; 1.8385x over previous
//
#include <hip/hip_runtime.h>

// ---------------- problem constants ----------------
#define Kc 8
#define Bc 64
#define Tc 128
#define Yc 128
#define Xc 64
#define Hc 256
#define Rc 8192   // B*T

typedef unsigned short u16;
typedef unsigned int u32;
typedef __attribute__((ext_vector_type(8))) short short8;  // 8 bf16 (4 VGPR)
typedef __attribute__((ext_vector_type(4))) float f32x4;   // MFMA C/D
typedef __attribute__((ext_vector_type(2))) unsigned int u32x2;

// ---------------- ws layout (u16 element offsets) ----------------
#define OFF_DATA 0L         // data bf16        [8192][128] row-major
#define OFF_YWIH 1048576L   // y_Wih bf16       [8][256][128] row-major
#define OFF_YWHH 1310720L   // y_Whh bf16       [8][256][256] row-major
#define OFF_YWMU 1835008L   // y_Wmu bf16       [8][64][256] row-major
#define OFF_XWIH 1966080L   // x_Wih bf16       [8][256][64] row-major
#define OFF_XWHH 2097152L   // x_Whh bf16       [8][256][256] row-major
#define OFF_M2   2621440L   // M2 = W2@dsW bf16 [16(pad)][2048] row-major
#define OFF_QXF  2654208L   // q_x bf16 frag tiles [8][4 bs][128 t][1024]
#define OFF_BUF1 6848512L   // xW_y -> h_y bf16 frag tiles [8][4 bs][128 t][4096] (in-place)
#define U16_BYTES 80805888L
// f32 region (after u16 region)
#define FO_YB 0L       // y bias (bih+bhh) [8][256]
#define FO_XB 2048L    // x bias           [8][256]
#define FO_CB 4096L    // combiner const   [16]
#define FO_A2 4112L    // A2 = W2@W1       [8][8]
#define FO_CP 8192L    // c partials       [8][8192][8]
#define FO_C  532480L  // c summed         [8192][8]
#define FO_W  598016L  // sparsemax w      [8192][8]

// frag-major tile (16 batch m x N hidden n):
//   u16 idx(m,n) = (n>>5)*512 + ((n>>3)&3)*128 + m*8 + (n&7)
// B-frag read (lane l, kk): idx = kk*512 + (l>>4)*128 + (l&15)*8  (16B contiguous)
// D write (lane l, nt): n = wv*64+nt*16+lk*4+r ->
//   roff = (wv*2+(nt>>1))*512 + ((nt&1)*2+(lk>>1))*128 + lr*8 + (lk&1)*4

// ---------------- output layout (f32 elements) ----------------
#define O_XS  0L        // x_sample   [64][128][64]
#define O_QMU 524288L   // q_x_mu     [8][64][128][64]
#define O_QLV 4718592L  // q_x_logvar [8][64][128][64] (zeros)
#define O_ZS  8912896L  // z_sample   [64][128][8]
#define O_ZL  8978432L  // z_logits   [64][128][8]

// ---------------- helpers ----------------
__device__ __forceinline__ u16 f2bf(float f) {
  union { float f; u32 u; } v; v.f = f;
  u32 u = v.u;
  return (u16)((u + 0x7FFFu + ((u >> 16) & 1u)) >> 16);  // RNE
}
__device__ __forceinline__ float bitsf(u32 u) {
  union { u32 u; float f; } v; v.u = u; return v.f;
}
__device__ __forceinline__ u32 cvt_pk(float lo, float hi) {
  u32 r;
  asm("v_cvt_pk_bf16_f32 %0, %1, %2" : "=v"(r) : "v"(lo), "v"(hi));
  return r;
}
__device__ __forceinline__ f32x4 mfma16(short8 a, short8 b, f32x4 c) {
  return __builtin_amdgcn_mfma_f32_16x16x32_bf16(a, b, c, 0, 0, 0);
}

// ---------------- P1: dtype conversions, biases, zero logvar ----------------
__global__ void k_prep(const float* __restrict__ data, const float* __restrict__ yWih,
                       const float* __restrict__ yWhh, const float* __restrict__ yWmu,
                       const float* __restrict__ xWih, const float* __restrict__ xWhh,
                       const float* __restrict__ ybih, const float* __restrict__ ybhh,
                       const float* __restrict__ xbih, const float* __restrict__ xbhh,
                       u16* __restrict__ W, float* __restrict__ F, float* __restrict__ out)
{
  long tid = (long)blockIdx.x * blockDim.x + threadIdx.x;
  long stride = (long)gridDim.x * blockDim.x;
  for (long i = tid; i < 1048576L; i += stride) W[OFF_DATA + i] = f2bf(data[i]);
  for (long i = tid; i < 262144L;  i += stride) W[OFF_YWIH + i] = f2bf(yWih[i]);
  for (long i = tid; i < 524288L;  i += stride) W[OFF_YWHH + i] = f2bf(yWhh[i]);
  for (long i = tid; i < 131072L;  i += stride) W[OFF_YWMU + i] = f2bf(yWmu[i]);
  for (long i = tid; i < 131072L;  i += stride) W[OFF_XWIH + i] = f2bf(xWih[i]);
  for (long i = tid; i < 524288L;  i += stride) W[OFF_XWHH + i] = f2bf(xWhh[i]);
  for (long i = tid; i < 2048L;    i += stride) F[FO_YB + i] = ybih[i] + ybhh[i];
  for (long i = tid; i < 2048L;    i += stride) F[FO_XB + i] = xbih[i] + xbhh[i];
  for (long i = tid; i < 4194304L; i += stride) out[O_QLV + i] = 0.0f;
}

// ---------------- P2: combiner collapse  M2 = W2@dsW,  A2 = W2@W1,  cbias ----------------
__global__ void k_prep2(const float* __restrict__ dsW, const float* __restrict__ dsb,
                        const float* __restrict__ W1, const float* __restrict__ b1,
                        const float* __restrict__ W2, const float* __restrict__ b2,
                        u16* __restrict__ W, float* __restrict__ F)
{
  if (blockIdx.x < 128) {  // M2 [16][2048] (rows >=8 zero-padded)
    long i = (long)blockIdx.x * 256 + threadIdx.x;   // 0..32767
    int k2 = (int)(i >> 11), ki = (int)(i & 2047);
    float s = 0.0f;
    if (k2 < 8) {
      for (int j = 0; j < 256; ++j) s += W2[k2 * 256 + j] * dsW[(long)j * 2048 + ki];
    }
    W[OFF_M2 + i] = f2bf(s);
  } else {  // blockIdx.x == 128
    int t = threadIdx.x;
    if (t < 64) {            // A2[k2][k1] = sum_j W2[k2,j] W1[j,k1]
      int k2 = t >> 3, k1 = t & 7;
      float s = 0.0f;
      for (int j = 0; j < 256; ++j) s += W2[k2 * 256 + j] * W1[j * 8 + k1];
      F[FO_A2 + t] = s;
    } else if (t < 80) {     // cbias[k2] = W2@(dsb+b1) + b2   (pad to 16)
      int k2 = t - 64;
      float s = 0.0f;
      if (k2 < 8) {
        for (int j = 0; j < 256; ++j) s += W2[k2 * 256 + j] * (dsb[j] + b1[j]);
        s += b2[k2];
      }
      F[FO_CB + k2] = s;
    }
  }
}

// ---------------- G1: xW_y = y_Wih(A) x data(B) + ybias -> buf1 frag tiles ----------------
__global__ __launch_bounds__(256) void k_g1(const u16* __restrict__ W, const float* __restrict__ F,
                                            u16* __restrict__ buf)
{
  const int k = blockIdx.y, bs = blockIdx.x >> 5, t0 = (blockIdx.x & 31) * 4;
  const int tid = threadIdx.x, wv = tid >> 6, l = tid & 63, lr = l & 15, lk = l >> 4;
  const int b0 = bs * 16;
  short8 Af[4][4];
  const u16* Ak = W + OFF_YWIH + (long)k * 32768;
#pragma unroll
  for (int nt = 0; nt < 4; ++nt)
#pragma unroll
    for (int kk = 0; kk < 4; ++kk)
      Af[nt][kk] = *(const short8*)(Ak + (long)(wv * 64 + nt * 16 + lr) * 128 + kk * 32 + lk * 8);
  f32x4 bias[4];
#pragma unroll
  for (int nt = 0; nt < 4; ++nt)
    bias[nt] = *(const f32x4*)&F[FO_YB + k * 256 + wv * 64 + nt * 16 + lk * 4];
  int roff[4];
#pragma unroll
  for (int nt = 0; nt < 4; ++nt)
    roff[nt] = (wv * 2 + (nt >> 1)) * 512 + ((nt & 1) * 2 + (lk >> 1)) * 128 + lr * 8 + (lk & 1) * 4;

  for (int ti = 0; ti < 4; ++ti) {
    int t = t0 + ti;
    f32x4 acc[4] = {bias[0], bias[1], bias[2], bias[3]};
    const u16* Brow = W + OFF_DATA + ((long)(b0 + lr) * 128 + t) * 128 + lk * 8;
#pragma unroll
    for (int kk = 0; kk < 4; ++kk) {
      short8 b = *(const short8*)(Brow + kk * 32);
      acc[0] = mfma16(Af[0][kk], b, acc[0]);
      acc[1] = mfma16(Af[1][kk], b, acc[1]);
      acc[2] = mfma16(Af[2][kk], b, acc[2]);
      acc[3] = mfma16(Af[3][kk], b, acc[3]);
    }
    u16* tb = buf + ((long)(k * 4 + bs) * 128 + t) * 4096;
#pragma unroll
    for (int nt = 0; nt < 4; ++nt) {
      u32 d0 = cvt_pk(acc[nt][0], acc[nt][1]);
      u32 d1 = cvt_pk(acc[nt][2], acc[nt][3]);
      *(u32x2*)(tb + roff[nt]) = (u32x2){d0, d1};
    }
  }
}

// ---------------- RY: backward ReLU y-RNN, in-place xW -> h, 2-deep prefetch ----------------
// grid (4 bs, 8 k), 256 thr. Unrolled x2: register sets xwA/xwB alternate; each sub-step
// consumes its set then re-issues load(t-2) into it -> vmcnt wait lands 2 step-bodies later.
#define RNNY_STEP(T_, XW_, PIN_, POUT_)                                       \
  {                                                                           \
    f32x4 acc[4];                                                             \
    _Pragma("unroll")                                                         \
    for (int nt = 0; nt < 4; ++nt) {                                          \
      u32 w0 = XW_[nt * 2], w1 = XW_[nt * 2 + 1];                             \
      acc[nt][0] = bitsf(w0 << 16);                                           \
      acc[nt][1] = bitsf(w0 & 0xffff0000u);                                   \
      acc[nt][2] = bitsf(w1 << 16);                                           \
      acc[nt][3] = bitsf(w1 & 0xffff0000u);                                   \
    }                                                                         \
    if ((T_) >= 2) {                                                          \
      _Pragma("unroll")                                                       \
      for (int nt = 0; nt < 4; ++nt) {                                        \
        u32x2 v = *(const u32x2*)(tb0 + (long)((T_) - 2) * 4096 + roff[nt]);  \
        XW_[nt * 2] = v.x; XW_[nt * 2 + 1] = v.y;                             \
      }                                                                       \
    }                                                                         \
    _Pragma("unroll")                                                         \
    for (int kk = 0; kk < 8; ++kk) {                                          \
      short8 b = *(const short8*)&hlds[PIN_][kk * 512 + fro];                 \
      acc[0] = mfma16(Bf[0][kk], b, acc[0]);                                  \
      acc[1] = mfma16(Bf[1][kk], b, acc[1]);                                  \
      acc[2] = mfma16(Bf[2][kk], b, acc[2]);                                  \
      acc[3] = mfma16(Bf[3][kk], b, acc[3]);                                  \
    }                                                                         \
    u16* tb = tb0 + (long)(T_) * 4096;                                        \
    _Pragma("unroll")                                                         \
    for (int nt = 0; nt < 4; ++nt) {                                          \
      float f0 = fmaxf(acc[nt][0], 0.0f), f1 = fmaxf(acc[nt][1], 0.0f);       \
      float f2 = fmaxf(acc[nt][2], 0.0f), f3 = fmaxf(acc[nt][3], 0.0f);       \
      u32x2 d = (u32x2){cvt_pk(f0, f1), cvt_pk(f2, f3)};                      \
      *(u32x2*)&hlds[POUT_][roff[nt]] = d;                                    \
      *(u32x2*)(tb + roff[nt]) = d;                                           \
    }                                                                         \
    asm volatile("s_waitcnt lgkmcnt(0)" ::: "memory");                        \
    __builtin_amdgcn_s_barrier();                                             \
    __builtin_amdgcn_sched_barrier(0);                                        \
  }

__global__ __launch_bounds__(256, 1) void k_rnnY(u16* __restrict__ buf,
                                                 const u16* __restrict__ Whh,
                                                 const float* __restrict__ h0)
{
  const int k = blockIdx.y, bs = blockIdx.x;
  const int tid = threadIdx.x, wv = tid >> 6, l = tid & 63, lr = l & 15, lk = l >> 4;
  const int fro = lk * 128 + lr * 8;
  __shared__ __align__(16) u16 hlds[2][4096];

  short8 Bf[4][8];
  const u16* Wk = Whh + (long)k * 65536;
#pragma unroll
  for (int nt = 0; nt < 4; ++nt)
#pragma unroll
    for (int kk = 0; kk < 8; ++kk)
      Bf[nt][kk] = *(const short8*)(Wk + (long)(wv * 64 + nt * 16 + lr) * 256 + kk * 32 + lk * 8);

  for (int i = tid; i < 4096; i += 256) {
    int n = (i >> 9) * 32 + ((i >> 7) & 3) * 8 + (i & 7);
    hlds[0][i] = f2bf(h0[k * 256 + n]);
  }

  u16* tb0 = buf + (long)(k * 4 + bs) * 128 * 4096;
  int roff[4];
#pragma unroll
  for (int nt = 0; nt < 4; ++nt)
    roff[nt] = (wv * 2 + (nt >> 1)) * 512 + ((nt & 1) * 2 + (lk >> 1)) * 128 + lr * 8 + (lk & 1) * 4;

  // pipeline fill: xwA = tile(127), xwB = tile(126)
  u32 xwA[8], xwB[8];
#pragma unroll
  for (int nt = 0; nt < 4; ++nt) {
    u32x2 vA = *(const u32x2*)(tb0 + (long)(Tc - 1) * 4096 + roff[nt]);
    xwA[nt * 2] = vA.x; xwA[nt * 2 + 1] = vA.y;
    u32x2 vB = *(const u32x2*)(tb0 + (long)(Tc - 2) * 4096 + roff[nt]);
    xwB[nt * 2] = vB.x; xwB[nt * 2 + 1] = vB.y;
  }
  __syncthreads();

  for (int t = Tc - 1; t >= 1; t -= 2) {
    RNNY_STEP(t, xwA, 0, 1);
    RNNY_STEP(t - 1, xwB, 1, 0);
  }
}

// ---------------- G2: q_x_mu = Wmu(A) x h_y(B) + bmu ; qx -> frag tiles (bf16) ----------------
__global__ __launch_bounds__(256) void k_g2(const u16* __restrict__ W, const u16* __restrict__ hy,
                                            const float* __restrict__ bmu, const float* __restrict__ eps,
                                            float* __restrict__ out, u16* __restrict__ qxf)
{
  const int k = blockIdx.y, bs = blockIdx.x >> 5, t0 = (blockIdx.x & 31) * 4;
  const int tid = threadIdx.x, wv = tid >> 6, l = tid & 63, lr = l & 15, lk = l >> 4;
  const int b0 = bs * 16, x0 = wv * 16;
  short8 Af[8];
  const u16* Ak = W + OFF_YWMU + (long)k * 16384;
#pragma unroll
  for (int kk = 0; kk < 8; ++kk)
    Af[kk] = *(const short8*)(Ak + (long)(x0 + lr) * 256 + kk * 32 + lk * 8);
  f32x4 bias = *(const f32x4*)&bmu[k * 64 + x0 + lk * 4];
  const int qoff = (wv >> 1) * 512 + ((wv & 1) * 2 + (lk >> 1)) * 128 + lr * 8 + (lk & 1) * 4;

  for (int ti = 0; ti < 4; ++ti) {
    int t = t0 + ti;
    const u16* tb = hy + ((long)(k * 4 + bs) * 128 + t) * 4096 + lk * 128 + lr * 8;
    f32x4 a0 = bias, a1 = (f32x4){0.f, 0.f, 0.f, 0.f};
#pragma unroll
    for (int kk = 0; kk < 8; kk += 2) {
      short8 bA = *(const short8*)(tb + kk * 512);
      short8 bB = *(const short8*)(tb + (kk + 1) * 512);
      a0 = mfma16(Af[kk], bA, a0);
      a1 = mfma16(Af[kk + 1], bB, a1);
    }
    f32x4 mu = a0 + a1;
    long idx = ((long)k * Rc + (b0 + lr) * 128 + t) * 64 + x0 + lk * 4;
    *(f32x4*)&out[O_QMU + idx] = mu;
    f32x4 e = *(const f32x4*)&eps[idx];
    f32x4 q = mu + e;
    *(u32x2*)(qxf + ((long)(k * 4 + bs) * 128 + t) * 1024 + qoff) =
        (u32x2){cvt_pk(q[0], q[1]), cvt_pk(q[2], q[3])};
  }
}

// ---------------- RX: backward ReLU x-RNN, fused input proj + M2 output, 2-deep prefetch ----------------
#define RNNX_STEP(T_, QC_, PIN_, POUT_)                                       \
  {                                                                           \
    short8 q0 = QC_[0], q1 = QC_[1];                                          \
    if ((T_) >= 2) {                                                          \
      QC_[0] = *(const short8*)(qb0 + (long)((T_) - 2) * 1024 + fro);         \
      QC_[1] = *(const short8*)(qb0 + (long)((T_) - 2) * 1024 + 512 + fro);   \
    }                                                                         \
    f32x4 acc[4] = {xbias[0], xbias[1], xbias[2], xbias[3]};                  \
    f32x4 cacc = (f32x4){0.f, 0.f, 0.f, 0.f};                                 \
    _Pragma("unroll")                                                         \
    for (int kk = 0; kk < 8; ++kk) {                                          \
      short8 b = *(const short8*)&hlds[PIN_][kk * 512 + fro];                 \
      acc[0] = mfma16(Bf[0][kk], b, acc[0]);                                  \
      acc[1] = mfma16(Bf[1][kk], b, acc[1]);                                  \
      acc[2] = mfma16(Bf[2][kk], b, acc[2]);                                  \
      acc[3] = mfma16(Bf[3][kk], b, acc[3]);                                  \
      if (wv == 0) cacc = mfma16(Mf[kk], b, cacc);                            \
    }                                                                         \
    acc[0] = mfma16(IhX[0][0], q0, acc[0]);                                   \
    acc[1] = mfma16(IhX[1][0], q0, acc[1]);                                   \
    acc[2] = mfma16(IhX[2][0], q0, acc[2]);                                   \
    acc[3] = mfma16(IhX[3][0], q0, acc[3]);                                   \
    acc[0] = mfma16(IhX[0][1], q1, acc[0]);                                   \
    acc[1] = mfma16(IhX[1][1], q1, acc[1]);                                   \
    acc[2] = mfma16(IhX[2][1], q1, acc[2]);                                   \
    acc[3] = mfma16(IhX[3][1], q1, acc[3]);                                   \
    if (wv == 0 && (T_) < Tc - 1 && lk < 2)                                   \
      *(f32x4*)&cp[((long)(b0 + lr) * Tc + (T_) + 1) * 8 + lk * 4] = cacc;    \
    _Pragma("unroll")                                                         \
    for (int nt = 0; nt < 4; ++nt) {                                          \
      float f0 = fmaxf(acc[nt][0], 0.0f), f1 = fmaxf(acc[nt][1], 0.0f);       \
      float f2 = fmaxf(acc[nt][2], 0.0f), f3 = fmaxf(acc[nt][3], 0.0f);       \
      *(u32x2*)&hlds[POUT_][roff[nt]] = (u32x2){cvt_pk(f0, f1), cvt_pk(f2, f3)}; \
    }                                                                         \
    asm volatile("s_waitcnt lgkmcnt(0)" ::: "memory");                        \
    __builtin_amdgcn_s_barrier();                                             \
    __builtin_amdgcn_sched_barrier(0);                                        \
  }

__global__ __launch_bounds__(256, 1) void k_rnnX(const u16* __restrict__ W,
                                                 const float* __restrict__ F,
                                                 const u16* __restrict__ qxf,
                                                 const float* __restrict__ h0,
                                                 float* __restrict__ cpart)
{
  const int k = blockIdx.y, bs = blockIdx.x, b0 = bs * 16;
  const int tid = threadIdx.x, wv = tid >> 6, l = tid & 63, lr = l & 15, lk = l >> 4;
  const int fro = lk * 128 + lr * 8;
  __shared__ __align__(16) u16 hlds[2][4096];

  short8 Bf[4][8];
  short8 IhX[4][2];
  short8 Mf[8];
  {
    const u16* Wk = W + OFF_XWHH + (long)k * 65536;
    const u16* Ik = W + OFF_XWIH + (long)k * 16384;
    const u16* Mk = W + OFF_M2 + (long)k * 256;
#pragma unroll
    for (int nt = 0; nt < 4; ++nt) {
#pragma unroll
      for (int kk = 0; kk < 8; ++kk)
        Bf[nt][kk] = *(const short8*)(Wk + (long)(wv * 64 + nt * 16 + lr) * 256 + kk * 32 + lk * 8);
#pragma unroll
      for (int kk = 0; kk < 2; ++kk)
        IhX[nt][kk] = *(const short8*)(Ik + (long)(wv * 64 + nt * 16 + lr) * 64 + kk * 32 + lk * 8);
    }
#pragma unroll
    for (int kk = 0; kk < 8; ++kk)
      Mf[kk] = *(const short8*)(Mk + (long)lr * 2048 + kk * 32 + lk * 8);
  }
  f32x4 xbias[4];
#pragma unroll
  for (int nt = 0; nt < 4; ++nt)
    xbias[nt] = *(const f32x4*)&F[FO_XB + k * 256 + wv * 64 + nt * 16 + lk * 4];
  int roff[4];
#pragma unroll
  for (int nt = 0; nt < 4; ++nt)
    roff[nt] = (wv * 2 + (nt >> 1)) * 512 + ((nt & 1) * 2 + (lk >> 1)) * 128 + lr * 8 + (lk & 1) * 4;

  for (int i = tid; i < 4096; i += 256) {
    int n = (i >> 9) * 32 + ((i >> 7) & 3) * 8 + (i & 7);
    hlds[0][i] = f2bf(h0[k * 256 + n]);
  }

  const u16* qb0 = qxf + (long)(k * 4 + bs) * 128 * 1024;
  float* cp = cpart + (long)k * Rc * 8;

  short8 qA[2], qB[2];
#pragma unroll
  for (int kk = 0; kk < 2; ++kk) {
    qA[kk] = *(const short8*)(qb0 + (long)(Tc - 1) * 1024 + kk * 512 + fro);
    qB[kk] = *(const short8*)(qb0 + (long)(Tc - 2) * 1024 + kk * 512 + fro);
  }
  __syncthreads();

  for (int t = Tc - 1; t >= 1; t -= 2) {
    RNNX_STEP(t, qA, 0, 1);
    RNNX_STEP(t - 1, qB, 1, 0);
  }
  // epilogue: c(0) from h(0) now in hlds[0]
  if (wv == 0) {
    f32x4 cacc = (f32x4){0.f, 0.f, 0.f, 0.f};
#pragma unroll
    for (int kk = 0; kk < 8; ++kk) {
      short8 b = *(const short8*)&hlds[0][kk * 512 + fro];
      cacc = mfma16(Mf[kk], b, cacc);
    }
    if (lk < 2)
      *(f32x4*)&cp[((long)(b0 + lr) * Tc) * 8 + lk * 4] = cacc;
  }
}

// ---------------- CS: c = cbias + sum_k cpart_k ----------------
__global__ void k_csum(const float* __restrict__ cpart, const float* __restrict__ F,
                       float* __restrict__ cbuf)
{
  int i = blockIdx.x * 256 + threadIdx.x;  // < 65536
  float s = F[FO_CB + (i & 7)];
#pragma unroll
  for (int k = 0; k < 8; ++k) s += cpart[(long)k * 65536 + i];
  cbuf[i] = s;
}

// ---------------- S5a: z chain (one wave per batch element) ----------------
#define CASD(a, b) { float _hi = fmaxf(a, b), _lo = fminf(a, b); a = _hi; b = _lo; }
__global__ __launch_bounds__(256) void k_zchain(const float* __restrict__ F, const float* __restrict__ cbuf,
                                                const float* __restrict__ eps_z, const float* __restrict__ zq0,
                                                float* __restrict__ out, float* __restrict__ wbuf)
{
  const int wv = threadIdx.x >> 6, l = threadIdx.x & 63;
  const int b = blockIdx.x * 4 + wv;
  __shared__ float cl[4][1024];
  __shared__ float el[4][1024];
  for (int i = l; i < 1024; i += 64) cl[wv][i] = cbuf[(long)b * 1024 + i];
  for (int i = l; i < 1024; i += 64) {
    int t = i >> 3, kk = i & 7;
    el[wv][i] = eps_z[(long)t * (Bc * Kc) + b * 8 + kk];
  }
  float a2 = F[FO_A2 + l];   // A2[l>>3][l&7]
  __syncthreads();

  float z = zq0[l & 7];      // every lane holds z_prev[l&7]
  for (int t = 0; t < Tc; ++t) {
    float p = a2 * z;
    p += __shfl_xor(p, 1, 64);
    p += __shfl_xor(p, 2, 64);
    p += __shfl_xor(p, 4, 64);                  // group g=l>>3 holds sum_k1 A2[g][k1] z[k1]
    float zmu_l = __shfl(p, (l & 7) * 8, 64);   // lane l gets zmu_lin[l&7]
    float zl = zmu_l + cl[wv][t * 8 + (l & 7)]; // z_logits
    float zt = zl + el[wv][t * 8 + (l & 7)];    // z_sample

    // sparsemax over 8 values (all lanes redundantly)
    float v0 = __shfl(zt, 0, 64), v1 = __shfl(zt, 1, 64), v2 = __shfl(zt, 2, 64), v3 = __shfl(zt, 3, 64);
    float v4 = __shfl(zt, 4, 64), v5 = __shfl(zt, 5, 64), v6 = __shfl(zt, 6, 64), v7 = __shfl(zt, 7, 64);
    CASD(v0, v1); CASD(v2, v3); CASD(v4, v5); CASD(v6, v7);
    CASD(v0, v2); CASD(v1, v3); CASD(v4, v6); CASD(v5, v7);
    CASD(v1, v2); CASD(v5, v6);
    CASD(v0, v4); CASD(v1, v5); CASD(v2, v6); CASD(v3, v7);
    CASD(v2, v4); CASD(v3, v5);
    CASD(v1, v2); CASD(v3, v4); CASD(v5, v6);   // v0 >= v1 >= ... >= v7
    float s0 = v0, s1 = s0 + v1, s2 = s1 + v2, s3 = s2 + v3;
    float s4 = s3 + v4, s5 = s4 + v5, s6 = s5 + v6, s7 = s6 + v7;
    int kz = 1;
    kz += (2.0f * v1 > s1 - 1.0f) ? 1 : 0;
    kz += (3.0f * v2 > s2 - 1.0f) ? 1 : 0;
    kz += (4.0f * v3 > s3 - 1.0f) ? 1 : 0;
    kz += (5.0f * v4 > s4 - 1.0f) ? 1 : 0;
    kz += (6.0f * v5 > s5 - 1.0f) ? 1 : 0;
    kz += (7.0f * v6 > s6 - 1.0f) ? 1 : 0;
    kz += (8.0f * v7 > s7 - 1.0f) ? 1 : 0;
    float csel = s0 - 1.0f;
    csel = (kz > 1) ? s1 - 1.0f : csel;
    csel = (kz > 2) ? s2 - 1.0f : csel;
    csel = (kz > 3) ? s3 - 1.0f : csel;
    csel = (kz > 4) ? s4 - 1.0f : csel;
    csel = (kz > 5) ? s5 - 1.0f : csel;
    csel = (kz > 6) ? s6 - 1.0f : csel;
    csel = (kz > 7) ? s7 - 1.0f : csel;
    float tau = csel / (float)kz;
    float wk = fmaxf(zt - tau, 0.0f);

    if (l < 8) {
      long r = (long)b * Tc + t;
      out[O_ZL + r * 8 + l] = zl;
      out[O_ZS + r * 8 + l] = zt;
      wbuf[r * 8 + l] = wk;
    }
    z = zt;
  }
}

// ---------------- S5b: x_sample = sum_k w * mu + eps_x ----------------
__global__ void k_xsample(const float* __restrict__ wbuf, const float* __restrict__ eps_x,
                          float* __restrict__ out)
{
  long idx = (long)blockIdx.x * 256 + threadIdx.x;
  if (idx >= (long)Rc * Xc) return;
  long r = idx >> 6;          // b*T + t
  int x = (int)(idx & 63);
  long b = r >> 7;
  long t = r & 127;
  float s = eps_x[(t * Bc + b) * 64 + x];
#pragma unroll
  for (int k = 0; k < 8; ++k)
    s += wbuf[r * 8 + k] * out[O_QMU + ((long)k * Rc + r) * 64 + x];
  out[O_XS + idx] = s;
}

// ---------------- launch ----------------
extern "C" void kernel_launch(void* const* d_in, const int* in_sizes, int n_in,
                              void* d_out, int out_size, void* d_ws, size_t ws_size,
                              hipStream_t stream) {
  (void)in_sizes; (void)n_in; (void)out_size; (void)ws_size;
  const float* data   = (const float*)d_in[0];
  const float* eps_qx = (const float*)d_in[1];
  const float* eps_z  = (const float*)d_in[2];
  const float* eps_x  = (const float*)d_in[3];
  const float* yWih   = (const float*)d_in[4];
  const float* yWhh   = (const float*)d_in[5];
  const float* ybih   = (const float*)d_in[6];
  const float* ybhh   = (const float*)d_in[7];
  const float* yh0    = (const float*)d_in[8];
  const float* yWmu   = (const float*)d_in[9];
  const float* ybmu   = (const float*)d_in[10];
  const float* xWih   = (const float*)d_in[11];
  const float* xWhh   = (const float*)d_in[12];
  const float* xbih   = (const float*)d_in[13];
  const float* xbhh   = (const float*)d_in[14];
  const float* xh0    = (const float*)d_in[15];
  const float* dsW    = (const float*)d_in[16];
  const float* dsb    = (const float*)d_in[17];
  const float* cbW1   = (const float*)d_in[18];
  const float* cbb1   = (const float*)d_in[19];
  const float* cbW2   = (const float*)d_in[20];
  const float* cbb2   = (const float*)d_in[21];
  const float* zq0    = (const float*)d_in[22];

  u16*   W = (u16*)d_ws;
  float* F = (float*)((char*)d_ws + U16_BYTES);
  float* out = (float*)d_out;

  hipLaunchKernelGGL(k_prep, dim3(1024), dim3(256), 0, stream,
                     data, yWih, yWhh, yWmu, xWih, xWhh, ybih, ybhh, xbih, xbhh, W, F, out);
  hipLaunchKernelGGL(k_prep2, dim3(129), dim3(256), 0, stream,
                     dsW, dsb, cbW1, cbb1, cbW2, cbb2, W, F);
  hipLaunchKernelGGL(k_g1, dim3(128, 8), dim3(256), 0, stream, W, F, W + OFF_BUF1);
  hipLaunchKernelGGL(k_rnnY, dim3(4, 8), dim3(256), 0, stream, W + OFF_BUF1, W + OFF_YWHH, yh0);
  hipLaunchKernelGGL(k_g2, dim3(128, 8), dim3(256), 0, stream,
                     W, W + OFF_BUF1, ybmu, eps_qx, out, W + OFF_QXF);
  hipLaunchKernelGGL(k_rnnX, dim3(4, 8), dim3(256), 0, stream,
                     W, F, W + OFF_QXF, xh0, F + FO_CP);
  hipLaunchKernelGGL(k_csum, dim3(256), dim3(256), 0, stream, F + FO_CP, F, F + FO_C);
  hipLaunchKernelGGL(k_zchain, dim3(16), dim3(256), 0, stream, F, F + FO_C, eps_z, zq0, out, F + FO_W);
  hipLaunchKernelGGL(k_xsample, dim3(2048), dim3(256), 0, stream, F + FO_W, eps_x, out);
}

// Round 11
// 284.580 us; speedup vs baseline: 2.1231x; 1.1548x over previous
//
#include <hip/hip_runtime.h>

// ---------------- problem constants ----------------
#define Kc 8
#define Bc 64
#define Tc 128
#define Yc 128
#define Xc 64
#define Hc 256
#define Rc 8192   // B*T

typedef unsigned short u16;
typedef unsigned int u32;
typedef __attribute__((ext_vector_type(8))) short short8;  // 8 bf16 (4 VGPR)
typedef __attribute__((ext_vector_type(4))) float f32x4;   // MFMA C/D
typedef __attribute__((ext_vector_type(2))) unsigned int u32x2;

// ---------------- ws layout (u16 element offsets) ----------------
#define OFF_DATA 0L         // data bf16        [8192][128] row-major
#define OFF_YWIH 1048576L   // y_Wih bf16       [8][256][128] row-major
#define OFF_YWHH 1310720L   // y_Whh bf16       [8][256][256] row-major
#define OFF_YWMU 1835008L   // y_Wmu bf16       [8][64][256] row-major
#define OFF_XWIH 1966080L   // x_Wih bf16       [8][256][64] row-major
#define OFF_XWHH 2097152L   // x_Whh bf16       [8][256][256] row-major
#define OFF_M2   2621440L   // M2 = W2@dsW bf16 [16(pad)][2048] row-major
#define OFF_QXF  2654208L   // q_x bf16 frag tiles [8][4 bs][128 t][1024]
#define OFF_BUF1 6848512L   // xW_y -> h_y bf16 frag tiles [8][4 bs][128 t][4096] (in-place)
#define U16_BYTES 80805888L
// f32 region (after u16 region)
#define FO_YB 0L       // y bias (bih+bhh) [8][256]
#define FO_XB 2048L    // x bias           [8][256]
#define FO_CB 4096L    // combiner const   [16]
#define FO_A2 4112L    // A2 = W2@W1       [8][8]
#define FO_CP 8192L    // c partials       [8][8192][8]
#define FO_W  598016L  // sparsemax w      [8192][8]

// frag-major tile (16 batch m x N hidden n):
//   u16 idx(m,n) = (n>>5)*512 + ((n>>3)&3)*128 + m*8 + (n&7)
// B-frag read (lane l, kk): idx = kk*512 + (l>>4)*128 + (l&15)*8  (16B contiguous)
// D write (8 waves, nt<2): n = wv*32+nt*16+lk*4+r ->
//   roff = wv*512 + (nt*2+(lk>>1))*128 + lr*8 + (lk&1)*4

// ---------------- output layout (f32 elements) ----------------
#define O_XS  0L        // x_sample   [64][128][64]
#define O_QMU 524288L   // q_x_mu     [8][64][128][64]
#define O_QLV 4718592L  // q_x_logvar [8][64][128][64] (zeros)
#define O_ZS  8912896L  // z_sample   [64][128][8]
#define O_ZL  8978432L  // z_logits   [64][128][8]

// ---------------- helpers ----------------
__device__ __forceinline__ u16 f2bf(float f) {
  union { float f; u32 u; } v; v.f = f;
  u32 u = v.u;
  return (u16)((u + 0x7FFFu + ((u >> 16) & 1u)) >> 16);  // RNE
}
__device__ __forceinline__ float bitsf(u32 u) {
  union { u32 u; float f; } v; v.u = u; return v.f;
}
__device__ __forceinline__ u32 cvt_pk(float lo, float hi) {
  u32 r;
  asm("v_cvt_pk_bf16_f32 %0, %1, %2" : "=v"(r) : "v"(lo), "v"(hi));
  return r;
}
__device__ __forceinline__ f32x4 mfma16(short8 a, short8 b, f32x4 c) {
  return __builtin_amdgcn_mfma_f32_16x16x32_bf16(a, b, c, 0, 0, 0);
}

// ---------------- P1: dtype conversions, biases, zero logvar ----------------
__global__ void k_prep(const float* __restrict__ data, const float* __restrict__ yWih,
                       const float* __restrict__ yWhh, const float* __restrict__ yWmu,
                       const float* __restrict__ xWih, const float* __restrict__ xWhh,
                       const float* __restrict__ ybih, const float* __restrict__ ybhh,
                       const float* __restrict__ xbih, const float* __restrict__ xbhh,
                       u16* __restrict__ W, float* __restrict__ F, float* __restrict__ out)
{
  long tid = (long)blockIdx.x * blockDim.x + threadIdx.x;
  long stride = (long)gridDim.x * blockDim.x;
  for (long i = tid; i < 1048576L; i += stride) W[OFF_DATA + i] = f2bf(data[i]);
  for (long i = tid; i < 262144L;  i += stride) W[OFF_YWIH + i] = f2bf(yWih[i]);
  for (long i = tid; i < 524288L;  i += stride) W[OFF_YWHH + i] = f2bf(yWhh[i]);
  for (long i = tid; i < 131072L;  i += stride) W[OFF_YWMU + i] = f2bf(yWmu[i]);
  for (long i = tid; i < 131072L;  i += stride) W[OFF_XWIH + i] = f2bf(xWih[i]);
  for (long i = tid; i < 524288L;  i += stride) W[OFF_XWHH + i] = f2bf(xWhh[i]);
  for (long i = tid; i < 2048L;    i += stride) F[FO_YB + i] = ybih[i] + ybhh[i];
  for (long i = tid; i < 2048L;    i += stride) F[FO_XB + i] = xbih[i] + xbhh[i];
  for (long i = tid; i < 4194304L; i += stride) out[O_QLV + i] = 0.0f;
}

// ---------------- P2: combiner collapse  M2 = W2@dsW,  A2 = W2@W1,  cbias ----------------
__global__ void k_prep2(const float* __restrict__ dsW, const float* __restrict__ dsb,
                        const float* __restrict__ W1, const float* __restrict__ b1,
                        const float* __restrict__ W2, const float* __restrict__ b2,
                        u16* __restrict__ W, float* __restrict__ F)
{
  if (blockIdx.x < 128) {  // M2 [16][2048] (rows >=8 zero-padded)
    long i = (long)blockIdx.x * 256 + threadIdx.x;   // 0..32767
    int k2 = (int)(i >> 11), ki = (int)(i & 2047);
    float s = 0.0f;
    if (k2 < 8) {
      for (int j = 0; j < 256; ++j) s += W2[k2 * 256 + j] * dsW[(long)j * 2048 + ki];
    }
    W[OFF_M2 + i] = f2bf(s);
  } else {  // blockIdx.x == 128
    int t = threadIdx.x;
    if (t < 64) {            // A2[k2][k1] = sum_j W2[k2,j] W1[j,k1]
      int k2 = t >> 3, k1 = t & 7;
      float s = 0.0f;
      for (int j = 0; j < 256; ++j) s += W2[k2 * 256 + j] * W1[j * 8 + k1];
      F[FO_A2 + t] = s;
    } else if (t < 80) {     // cbias[k2] = W2@(dsb+b1) + b2   (pad to 16)
      int k2 = t - 64;
      float s = 0.0f;
      if (k2 < 8) {
        for (int j = 0; j < 256; ++j) s += W2[k2 * 256 + j] * (dsb[j] + b1[j]);
        s += b2[k2];
      }
      F[FO_CB + k2] = s;
    }
  }
}

// ---------------- G1: xW_y = y_Wih(A) x data(B) + ybias -> buf1 frag tiles ----------------
__global__ __launch_bounds__(256) void k_g1(const u16* __restrict__ W, const float* __restrict__ F,
                                            u16* __restrict__ buf)
{
  const int k = blockIdx.y, bs = blockIdx.x >> 5, t0 = (blockIdx.x & 31) * 4;
  const int tid = threadIdx.x, wv = tid >> 6, l = tid & 63, lr = l & 15, lk = l >> 4;
  const int b0 = bs * 16;
  short8 Af[4][4];
  const u16* Ak = W + OFF_YWIH + (long)k * 32768;
#pragma unroll
  for (int nt = 0; nt < 4; ++nt)
#pragma unroll
    for (int kk = 0; kk < 4; ++kk)
      Af[nt][kk] = *(const short8*)(Ak + (long)(wv * 64 + nt * 16 + lr) * 128 + kk * 32 + lk * 8);
  f32x4 bias[4];
#pragma unroll
  for (int nt = 0; nt < 4; ++nt)
    bias[nt] = *(const f32x4*)&F[FO_YB + k * 256 + wv * 64 + nt * 16 + lk * 4];
  int roff[4];
#pragma unroll
  for (int nt = 0; nt < 4; ++nt)
    roff[nt] = (wv * 2 + (nt >> 1)) * 512 + ((nt & 1) * 2 + (lk >> 1)) * 128 + lr * 8 + (lk & 1) * 4;

  for (int ti = 0; ti < 4; ++ti) {
    int t = t0 + ti;
    f32x4 acc[4] = {bias[0], bias[1], bias[2], bias[3]};
    const u16* Brow = W + OFF_DATA + ((long)(b0 + lr) * 128 + t) * 128 + lk * 8;
#pragma unroll
    for (int kk = 0; kk < 4; ++kk) {
      short8 b = *(const short8*)(Brow + kk * 32);
      acc[0] = mfma16(Af[0][kk], b, acc[0]);
      acc[1] = mfma16(Af[1][kk], b, acc[1]);
      acc[2] = mfma16(Af[2][kk], b, acc[2]);
      acc[3] = mfma16(Af[3][kk], b, acc[3]);
    }
    u16* tb = buf + ((long)(k * 4 + bs) * 128 + t) * 4096;
#pragma unroll
    for (int nt = 0; nt < 4; ++nt) {
      u32 d0 = cvt_pk(acc[nt][0], acc[nt][1]);
      u32 d1 = cvt_pk(acc[nt][2], acc[nt][3]);
      *(u32x2*)(tb + roff[nt]) = (u32x2){d0, d1};
    }
  }
}

// ---------------- RY: backward ReLU y-RNN, 8 waves (2 waves/SIMD), 2-deep prefetch ----------------
// grid (4 bs, 8 k), 512 thr: wave wv owns n-stripe [wv*32, wv*32+32).
#define RNNY_STEP(T_, XW_, PIN_, POUT_)                                       \
  {                                                                           \
    f32x4 acc0, acc1;                                                         \
    { u32 w0 = XW_[0], w1 = XW_[1];                                           \
      acc0[0] = bitsf(w0 << 16); acc0[1] = bitsf(w0 & 0xffff0000u);           \
      acc0[2] = bitsf(w1 << 16); acc0[3] = bitsf(w1 & 0xffff0000u); }         \
    { u32 w0 = XW_[2], w1 = XW_[3];                                           \
      acc1[0] = bitsf(w0 << 16); acc1[1] = bitsf(w0 & 0xffff0000u);           \
      acc1[2] = bitsf(w1 << 16); acc1[3] = bitsf(w1 & 0xffff0000u); }         \
    if ((T_) >= 2) {                                                          \
      u32x2 v0 = *(const u32x2*)(tb0 + (long)((T_) - 2) * 4096 + roff[0]);    \
      u32x2 v1 = *(const u32x2*)(tb0 + (long)((T_) - 2) * 4096 + roff[1]);    \
      XW_[0] = v0.x; XW_[1] = v0.y; XW_[2] = v1.x; XW_[3] = v1.y;             \
    }                                                                         \
    _Pragma("unroll")                                                         \
    for (int kk = 0; kk < 8; ++kk) {                                          \
      short8 b = *(const short8*)&hlds[PIN_][kk * 512 + fro];                 \
      acc0 = mfma16(Bf[0][kk], b, acc0);                                      \
      acc1 = mfma16(Bf[1][kk], b, acc1);                                      \
    }                                                                         \
    u16* tb = tb0 + (long)(T_) * 4096;                                        \
    { u32x2 d = (u32x2){cvt_pk(fmaxf(acc0[0], 0.f), fmaxf(acc0[1], 0.f)),     \
                        cvt_pk(fmaxf(acc0[2], 0.f), fmaxf(acc0[3], 0.f))};    \
      *(u32x2*)&hlds[POUT_][roff[0]] = d; *(u32x2*)(tb + roff[0]) = d; }      \
    { u32x2 d = (u32x2){cvt_pk(fmaxf(acc1[0], 0.f), fmaxf(acc1[1], 0.f)),     \
                        cvt_pk(fmaxf(acc1[2], 0.f), fmaxf(acc1[3], 0.f))};    \
      *(u32x2*)&hlds[POUT_][roff[1]] = d; *(u32x2*)(tb + roff[1]) = d; }      \
    asm volatile("s_waitcnt lgkmcnt(0)" ::: "memory");                        \
    __builtin_amdgcn_s_barrier();                                             \
    __builtin_amdgcn_sched_barrier(0);                                        \
  }

__global__ __launch_bounds__(512, 1) void k_rnnY(u16* __restrict__ buf,
                                                 const u16* __restrict__ Whh,
                                                 const float* __restrict__ h0)
{
  const int k = blockIdx.y, bs = blockIdx.x;
  const int tid = threadIdx.x, wv = tid >> 6, l = tid & 63, lr = l & 15, lk = l >> 4;
  const int fro = lk * 128 + lr * 8;
  __shared__ __align__(16) u16 hlds[2][4096];

  short8 Bf[2][8];
  const u16* Wk = Whh + (long)k * 65536;
#pragma unroll
  for (int nt = 0; nt < 2; ++nt)
#pragma unroll
    for (int kk = 0; kk < 8; ++kk)
      Bf[nt][kk] = *(const short8*)(Wk + (long)(wv * 32 + nt * 16 + lr) * 256 + kk * 32 + lk * 8);

  for (int i = tid; i < 4096; i += 512) {
    int n = (i >> 9) * 32 + ((i >> 7) & 3) * 8 + (i & 7);
    hlds[0][i] = f2bf(h0[k * 256 + n]);
  }

  u16* tb0 = buf + (long)(k * 4 + bs) * 128 * 4096;
  int roff[2];
#pragma unroll
  for (int nt = 0; nt < 2; ++nt)
    roff[nt] = wv * 512 + (nt * 2 + (lk >> 1)) * 128 + lr * 8 + (lk & 1) * 4;

  // pipeline fill: xwA = tile(127), xwB = tile(126)
  u32 xwA[4], xwB[4];
  {
    u32x2 a0 = *(const u32x2*)(tb0 + (long)(Tc - 1) * 4096 + roff[0]);
    u32x2 a1 = *(const u32x2*)(tb0 + (long)(Tc - 1) * 4096 + roff[1]);
    xwA[0] = a0.x; xwA[1] = a0.y; xwA[2] = a1.x; xwA[3] = a1.y;
    u32x2 b0v = *(const u32x2*)(tb0 + (long)(Tc - 2) * 4096 + roff[0]);
    u32x2 b1v = *(const u32x2*)(tb0 + (long)(Tc - 2) * 4096 + roff[1]);
    xwB[0] = b0v.x; xwB[1] = b0v.y; xwB[2] = b1v.x; xwB[3] = b1v.y;
  }
  __syncthreads();

  for (int t = Tc - 1; t >= 1; t -= 2) {
    RNNY_STEP(t, xwA, 0, 1);
    RNNY_STEP(t - 1, xwB, 1, 0);
  }
}

// ---------------- G2: q_x_mu = Wmu(A) x h_y(B) + bmu ; qx -> frag tiles (bf16) ----------------
__global__ __launch_bounds__(256) void k_g2(const u16* __restrict__ W, const u16* __restrict__ hy,
                                            const float* __restrict__ bmu, const float* __restrict__ eps,
                                            float* __restrict__ out, u16* __restrict__ qxf)
{
  const int k = blockIdx.y, bs = blockIdx.x >> 5, t0 = (blockIdx.x & 31) * 4;
  const int tid = threadIdx.x, wv = tid >> 6, l = tid & 63, lr = l & 15, lk = l >> 4;
  const int b0 = bs * 16, x0 = wv * 16;
  short8 Af[8];
  const u16* Ak = W + OFF_YWMU + (long)k * 16384;
#pragma unroll
  for (int kk = 0; kk < 8; ++kk)
    Af[kk] = *(const short8*)(Ak + (long)(x0 + lr) * 256 + kk * 32 + lk * 8);
  f32x4 bias = *(const f32x4*)&bmu[k * 64 + x0 + lk * 4];
  const int qoff = (wv >> 1) * 512 + ((wv & 1) * 2 + (lk >> 1)) * 128 + lr * 8 + (lk & 1) * 4;

  for (int ti = 0; ti < 4; ++ti) {
    int t = t0 + ti;
    const u16* tb = hy + ((long)(k * 4 + bs) * 128 + t) * 4096 + lk * 128 + lr * 8;
    f32x4 a0 = bias, a1 = (f32x4){0.f, 0.f, 0.f, 0.f};
#pragma unroll
    for (int kk = 0; kk < 8; kk += 2) {
      short8 bA = *(const short8*)(tb + kk * 512);
      short8 bB = *(const short8*)(tb + (kk + 1) * 512);
      a0 = mfma16(Af[kk], bA, a0);
      a1 = mfma16(Af[kk + 1], bB, a1);
    }
    f32x4 mu = a0 + a1;
    long idx = ((long)k * Rc + (b0 + lr) * 128 + t) * 64 + x0 + lk * 4;
    *(f32x4*)&out[O_QMU + idx] = mu;
    f32x4 e = *(const f32x4*)&eps[idx];
    f32x4 q = mu + e;
    *(u32x2*)(qxf + ((long)(k * 4 + bs) * 128 + t) * 1024 + qoff) =
        (u32x2){cvt_pk(q[0], q[1]), cvt_pk(q[2], q[3])};
  }
}

// ---------------- RX: backward ReLU x-RNN, 8 waves, fused input proj + M2, 2-deep prefetch ----------------
#define RNNX_STEP(T_, QC_, PIN_, POUT_)                                       \
  {                                                                           \
    short8 q0 = QC_[0], q1 = QC_[1];                                          \
    if ((T_) >= 2) {                                                          \
      QC_[0] = *(const short8*)(qb0 + (long)((T_) - 2) * 1024 + fro);         \
      QC_[1] = *(const short8*)(qb0 + (long)((T_) - 2) * 1024 + 512 + fro);   \
    }                                                                         \
    f32x4 acc0 = xbias[0], acc1 = xbias[1];                                   \
    f32x4 cacc = (f32x4){0.f, 0.f, 0.f, 0.f};                                 \
    _Pragma("unroll")                                                         \
    for (int kk = 0; kk < 8; ++kk) {                                          \
      short8 b = *(const short8*)&hlds[PIN_][kk * 512 + fro];                 \
      acc0 = mfma16(Bf[0][kk], b, acc0);                                      \
      acc1 = mfma16(Bf[1][kk], b, acc1);                                      \
      if (wv == 0) cacc = mfma16(Mf[kk], b, cacc);                            \
    }                                                                         \
    acc0 = mfma16(IhX[0][0], q0, acc0);                                       \
    acc1 = mfma16(IhX[1][0], q0, acc1);                                       \
    acc0 = mfma16(IhX[0][1], q1, acc0);                                       \
    acc1 = mfma16(IhX[1][1], q1, acc1);                                       \
    if (wv == 0 && (T_) < Tc - 1 && lk < 2)                                   \
      *(f32x4*)&cp[((long)(b0 + lr) * Tc + (T_) + 1) * 8 + lk * 4] = cacc;    \
    { u32x2 d = (u32x2){cvt_pk(fmaxf(acc0[0], 0.f), fmaxf(acc0[1], 0.f)),     \
                        cvt_pk(fmaxf(acc0[2], 0.f), fmaxf(acc0[3], 0.f))};    \
      *(u32x2*)&hlds[POUT_][roff[0]] = d; }                                   \
    { u32x2 d = (u32x2){cvt_pk(fmaxf(acc1[0], 0.f), fmaxf(acc1[1], 0.f)),     \
                        cvt_pk(fmaxf(acc1[2], 0.f), fmaxf(acc1[3], 0.f))};    \
      *(u32x2*)&hlds[POUT_][roff[1]] = d; }                                   \
    asm volatile("s_waitcnt lgkmcnt(0)" ::: "memory");                        \
    __builtin_amdgcn_s_barrier();                                             \
    __builtin_amdgcn_sched_barrier(0);                                        \
  }

__global__ __launch_bounds__(512, 1) void k_rnnX(const u16* __restrict__ W,
                                                 const float* __restrict__ F,
                                                 const u16* __restrict__ qxf,
                                                 const float* __restrict__ h0,
                                                 float* __restrict__ cpart)
{
  const int k = blockIdx.y, bs = blockIdx.x, b0 = bs * 16;
  const int tid = threadIdx.x, wv = tid >> 6, l = tid & 63, lr = l & 15, lk = l >> 4;
  const int fro = lk * 128 + lr * 8;
  __shared__ __align__(16) u16 hlds[2][4096];

  short8 Bf[2][8];
  short8 IhX[2][2];
  short8 Mf[8];
  {
    const u16* Wk = W + OFF_XWHH + (long)k * 65536;
    const u16* Ik = W + OFF_XWIH + (long)k * 16384;
    const u16* Mk = W + OFF_M2 + (long)k * 256;
#pragma unroll
    for (int nt = 0; nt < 2; ++nt) {
#pragma unroll
      for (int kk = 0; kk < 8; ++kk)
        Bf[nt][kk] = *(const short8*)(Wk + (long)(wv * 32 + nt * 16 + lr) * 256 + kk * 32 + lk * 8);
#pragma unroll
      for (int kk = 0; kk < 2; ++kk)
        IhX[nt][kk] = *(const short8*)(Ik + (long)(wv * 32 + nt * 16 + lr) * 64 + kk * 32 + lk * 8);
    }
#pragma unroll
    for (int kk = 0; kk < 8; ++kk)
      Mf[kk] = *(const short8*)(Mk + (long)lr * 2048 + kk * 32 + lk * 8);
  }
  f32x4 xbias[2];
#pragma unroll
  for (int nt = 0; nt < 2; ++nt)
    xbias[nt] = *(const f32x4*)&F[FO_XB + k * 256 + wv * 32 + nt * 16 + lk * 4];
  int roff[2];
#pragma unroll
  for (int nt = 0; nt < 2; ++nt)
    roff[nt] = wv * 512 + (nt * 2 + (lk >> 1)) * 128 + lr * 8 + (lk & 1) * 4;

  for (int i = tid; i < 4096; i += 512) {
    int n = (i >> 9) * 32 + ((i >> 7) & 3) * 8 + (i & 7);
    hlds[0][i] = f2bf(h0[k * 256 + n]);
  }

  const u16* qb0 = qxf + (long)(k * 4 + bs) * 128 * 1024;
  float* cp = cpart + (long)k * Rc * 8;

  short8 qA[2], qB[2];
#pragma unroll
  for (int kk = 0; kk < 2; ++kk) {
    qA[kk] = *(const short8*)(qb0 + (long)(Tc - 1) * 1024 + kk * 512 + fro);
    qB[kk] = *(const short8*)(qb0 + (long)(Tc - 2) * 1024 + kk * 512 + fro);
  }
  __syncthreads();

  for (int t = Tc - 1; t >= 1; t -= 2) {
    RNNX_STEP(t, qA, 0, 1);
    RNNX_STEP(t - 1, qB, 1, 0);
  }
  // epilogue: c(0) from h(0) now in hlds[0]
  if (wv == 0) {
    f32x4 cacc = (f32x4){0.f, 0.f, 0.f, 0.f};
#pragma unroll
    for (int kk = 0; kk < 8; ++kk) {
      short8 b = *(const short8*)&hlds[0][kk * 512 + fro];
      cacc = mfma16(Mf[kk], b, cacc);
    }
    if (lk < 2)
      *(f32x4*)&cp[((long)(b0 + lr) * Tc) * 8 + lk * 4] = cacc;
  }
}

// ---------------- S5a: z chain (one wave per batch element; csum folded in) ----------------
#define CASD(a, b) { float _hi = fmaxf(a, b), _lo = fminf(a, b); a = _hi; b = _lo; }
__global__ __launch_bounds__(256) void k_zchain(const float* __restrict__ F, const float* __restrict__ cpart,
                                                const float* __restrict__ eps_z, const float* __restrict__ zq0,
                                                float* __restrict__ out, float* __restrict__ wbuf)
{
  const int wv = threadIdx.x >> 6, l = threadIdx.x & 63;
  const int b = blockIdx.x * 4 + wv;
  __shared__ float cl[4][1024];
  __shared__ float el[4][1024];
  for (int i = l; i < 1024; i += 64) {
    float s = F[FO_CB + (i & 7)];
#pragma unroll
    for (int kq = 0; kq < 8; ++kq) s += cpart[(long)kq * 65536 + (long)b * 1024 + i];
    cl[wv][i] = s;
  }
  for (int i = l; i < 1024; i += 64) {
    int t = i >> 3, kk = i & 7;
    el[wv][i] = eps_z[(long)t * (Bc * Kc) + b * 8 + kk];
  }
  float a2 = F[FO_A2 + l];   // A2[l>>3][l&7]
  __syncthreads();

  float z = zq0[l & 7];      // every lane holds z_prev[l&7]
  for (int t = 0; t < Tc; ++t) {
    float p = a2 * z;
    p += __shfl_xor(p, 1, 64);
    p += __shfl_xor(p, 2, 64);
    p += __shfl_xor(p, 4, 64);                  // group g=l>>3 holds sum_k1 A2[g][k1] z[k1]
    float zmu_l = __shfl(p, (l & 7) * 8, 64);   // lane l gets zmu_lin[l&7]
    float zl = zmu_l + cl[wv][t * 8 + (l & 7)]; // z_logits
    float zt = zl + el[wv][t * 8 + (l & 7)];    // z_sample

    // sparsemax over 8 values (all lanes redundantly)
    float v0 = __shfl(zt, 0, 64), v1 = __shfl(zt, 1, 64), v2 = __shfl(zt, 2, 64), v3 = __shfl(zt, 3, 64);
    float v4 = __shfl(zt, 4, 64), v5 = __shfl(zt, 5, 64), v6 = __shfl(zt, 6, 64), v7 = __shfl(zt, 7, 64);
    CASD(v0, v1); CASD(v2, v3); CASD(v4, v5); CASD(v6, v7);
    CASD(v0, v2); CASD(v1, v3); CASD(v4, v6); CASD(v5, v7);
    CASD(v1, v2); CASD(v5, v6);
    CASD(v0, v4); CASD(v1, v5); CASD(v2, v6); CASD(v3, v7);
    CASD(v2, v4); CASD(v3, v5);
    CASD(v1, v2); CASD(v3, v4); CASD(v5, v6);   // v0 >= v1 >= ... >= v7
    float s0 = v0, s1 = s0 + v1, s2 = s1 + v2, s3 = s2 + v3;
    float s4 = s3 + v4, s5 = s4 + v5, s6 = s5 + v6, s7 = s6 + v7;
    int kz = 1;
    kz += (2.0f * v1 > s1 - 1.0f) ? 1 : 0;
    kz += (3.0f * v2 > s2 - 1.0f) ? 1 : 0;
    kz += (4.0f * v3 > s3 - 1.0f) ? 1 : 0;
    kz += (5.0f * v4 > s4 - 1.0f) ? 1 : 0;
    kz += (6.0f * v5 > s5 - 1.0f) ? 1 : 0;
    kz += (7.0f * v6 > s6 - 1.0f) ? 1 : 0;
    kz += (8.0f * v7 > s7 - 1.0f) ? 1 : 0;
    float csel = s0 - 1.0f;
    csel = (kz > 1) ? s1 - 1.0f : csel;
    csel = (kz > 2) ? s2 - 1.0f : csel;
    csel = (kz > 3) ? s3 - 1.0f : csel;
    csel = (kz > 4) ? s4 - 1.0f : csel;
    csel = (kz > 5) ? s5 - 1.0f : csel;
    csel = (kz > 6) ? s6 - 1.0f : csel;
    csel = (kz > 7) ? s7 - 1.0f : csel;
    float tau = csel / (float)kz;
    float wk = fmaxf(zt - tau, 0.0f);

    if (l < 8) {
      long r = (long)b * Tc + t;
      out[O_ZL + r * 8 + l] = zl;
      out[O_ZS + r * 8 + l] = zt;
      wbuf[r * 8 + l] = wk;
    }
    z = zt;
  }
}

// ---------------- S5b: x_sample = sum_k w * mu + eps_x ----------------
__global__ void k_xsample(const float* __restrict__ wbuf, const float* __restrict__ eps_x,
                          float* __restrict__ out)
{
  long idx = (long)blockIdx.x * 256 + threadIdx.x;
  if (idx >= (long)Rc * Xc) return;
  long r = idx >> 6;          // b*T + t
  int x = (int)(idx & 63);
  long b = r >> 7;
  long t = r & 127;
  float s = eps_x[(t * Bc + b) * 64 + x];
#pragma unroll
  for (int k = 0; k < 8; ++k)
    s += wbuf[r * 8 + k] * out[O_QMU + ((long)k * Rc + r) * 64 + x];
  out[O_XS + idx] = s;
}

// ---------------- launch ----------------
extern "C" void kernel_launch(void* const* d_in, const int* in_sizes, int n_in,
                              void* d_out, int out_size, void* d_ws, size_t ws_size,
                              hipStream_t stream) {
  (void)in_sizes; (void)n_in; (void)out_size; (void)ws_size;
  const float* data   = (const float*)d_in[0];
  const float* eps_qx = (const float*)d_in[1];
  const float* eps_z  = (const float*)d_in[2];
  const float* eps_x  = (const float*)d_in[3];
  const float* yWih   = (const float*)d_in[4];
  const float* yWhh   = (const float*)d_in[5];
  const float* ybih   = (const float*)d_in[6];
  const float* ybhh   = (const float*)d_in[7];
  const float* yh0    = (const float*)d_in[8];
  const float* yWmu   = (const float*)d_in[9];
  const float* ybmu   = (const float*)d_in[10];
  const float* xWih   = (const float*)d_in[11];
  const float* xWhh   = (const float*)d_in[12];
  const float* xbih   = (const float*)d_in[13];
  const float* xbhh   = (const float*)d_in[14];
  const float* xh0    = (const float*)d_in[15];
  const float* dsW    = (const float*)d_in[16];
  const float* dsb    = (const float*)d_in[17];
  const float* cbW1   = (const float*)d_in[18];
  const float* cbb1   = (const float*)d_in[19];
  const float* cbW2   = (const float*)d_in[20];
  const float* cbb2   = (const float*)d_in[21];
  const float* zq0    = (const float*)d_in[22];

  u16*   W = (u16*)d_ws;
  float* F = (float*)((char*)d_ws + U16_BYTES);
  float* out = (float*)d_out;

  hipLaunchKernelGGL(k_prep, dim3(1024), dim3(256), 0, stream,
                     data, yWih, yWhh, yWmu, xWih, xWhh, ybih, ybhh, xbih, xbhh, W, F, out);
  hipLaunchKernelGGL(k_prep2, dim3(129), dim3(256), 0, stream,
                     dsW, dsb, cbW1, cbb1, cbW2, cbb2, W, F);
  hipLaunchKernelGGL(k_g1, dim3(128, 8), dim3(256), 0, stream, W, F, W + OFF_BUF1);
  hipLaunchKernelGGL(k_rnnY, dim3(4, 8), dim3(512), 0, stream, W + OFF_BUF1, W + OFF_YWHH, yh0);
  hipLaunchKernelGGL(k_g2, dim3(128, 8), dim3(256), 0, stream,
                     W, W + OFF_BUF1, ybmu, eps_qx, out, W + OFF_QXF);
  hipLaunchKernelGGL(k_rnnX, dim3(4, 8), dim3(512), 0, stream,
                     W, F, W + OFF_QXF, xh0, F + FO_CP);
  hipLaunchKernelGGL(k_zchain, dim3(16), dim3(256), 0, stream, F, F + FO_CP, eps_z, zq0, out, F + FO_W);
  hipLaunchKernelGGL(k_xsample, dim3(2048), dim3(256), 0, stream, F + FO_W, eps_x, out);
}